// Round 2
// baseline (376.645 us; speedup 1.0000x reference)
//
#include <hip/hip_runtime.h>

// out[b,m,c] = sum_{k<3} vals[m,k] * x[b, cols[m,k], c]
// B=8, N=50000, C=128, M=25000, K=3, fp32.
//
// Two-phase: (1) transpose x[b][n][c] -> xt[n][b][c] in ws (streaming both
// ways), (2) gather with 4 KB granules (xt row = all 8 batches contiguous).
// This turns 600k random 512B reads into 75k random 4KB reads.

#define B_ 8
#define N_ 50000
#define C_ 128
#define M_ 25000
#define GPM 8   // m's per block in phase 2

// Phase 1: block n copies x[0:8, n, 0:128] -> xt[n, 0:8, 0:128].
// thread t: b = t>>5, c4 = t&31.  Write is 4 KB fully contiguous per block;
// reads are 8 sequential streams (one per b) as n advances.
__global__ __launch_bounds__(256) void transpose_kernel(
    const float* __restrict__ x, float* __restrict__ xt)
{
    int n = blockIdx.x;
    int t = threadIdx.x;
    int b = t >> 5, c4 = t & 31;
    float4 v = ((const float4*)x)[((long long)b * N_ + n) * 32 + c4];
    ((float4*)xt)[(long long)n * 256 + t] = v;
}

// Phase 2: block handles GPM consecutive m's. For each (m,k) the whole block
// reads xt[i_k] (4 KB contiguous, uniform base + lane offset). Thread t owns
// (b = t>>5, c4 = t&31) of the output row.
__global__ __launch_bounds__(256) void gather_kernel(
    const float* __restrict__ xt,
    const int* __restrict__ cols,
    const float* __restrict__ vals,
    float* __restrict__ out)
{
    int m0 = blockIdx.x * GPM;
    int t = threadIdx.x;
    int b = t >> 5, c4 = t & 31;
    const float4* xt4 = (const float4*)xt;
    float4* out4 = (float4*)out;

    #pragma unroll 2
    for (int j = 0; j < GPM; ++j) {
        int m = m0 + j;
        // m is block-uniform -> these become scalar loads
        int i0 = cols[m * 3 + 0];
        int i1 = cols[m * 3 + 1];
        int i2 = cols[m * 3 + 2];
        float v0 = vals[m * 3 + 0];
        float v1 = vals[m * 3 + 1];
        float v2 = vals[m * 3 + 2];

        float4 a = xt4[(long long)i0 * 256 + t];
        float4 q = xt4[(long long)i1 * 256 + t];
        float4 w = xt4[(long long)i2 * 256 + t];

        float4 r;
        r.x = v0 * a.x + v1 * q.x + v2 * w.x;
        r.y = v0 * a.y + v1 * q.y + v2 * w.y;
        r.z = v0 * a.z + v1 * q.z + v2 * w.z;
        r.w = v0 * a.w + v1 * q.w + v2 * w.w;

        out4[((long long)b * M_ + m) * 32 + c4] = r;
    }
}

// Fallback (round-1 kernel, passing at 305 us) if ws is too small for xt.
__global__ __launch_bounds__(256) void mesh_gather_direct(
    const float* __restrict__ x,
    const int* __restrict__ cols,
    const float* __restrict__ vals,
    float* __restrict__ out)
{
    int t = blockIdx.x * blockDim.x + threadIdx.x;
    const int total = B_ * M_ * (C_ / 4);
    if (t >= total) return;

    int c4 = t & 31;
    int m  = (t >> 5) % M_;
    int b  = t / (M_ * 32);

    int i0 = cols[m * 3 + 0];
    int i1 = cols[m * 3 + 1];
    int i2 = cols[m * 3 + 2];
    float v0 = vals[m * 3 + 0];
    float v1 = vals[m * 3 + 1];
    float v2 = vals[m * 3 + 2];

    const float4* xb = (const float4*)(x + (long long)b * N_ * C_);
    float4 a = xb[(long long)i0 * 32 + c4];
    float4 q = xb[(long long)i1 * 32 + c4];
    float4 w = xb[(long long)i2 * 32 + c4];

    float4 r;
    r.x = v0 * a.x + v1 * q.x + v2 * w.x;
    r.y = v0 * a.y + v1 * q.y + v2 * w.y;
    r.z = v0 * a.z + v1 * q.z + v2 * w.z;
    r.w = v0 * a.w + v1 * q.w + v2 * w.w;

    ((float4*)out)[t] = r;
}

extern "C" void kernel_launch(void* const* d_in, const int* in_sizes, int n_in,
                              void* d_out, int out_size, void* d_ws, size_t ws_size,
                              hipStream_t stream) {
    const float* x    = (const float*)d_in[0];
    const int*   cols = (const int*)d_in[1];
    const float* vals = (const float*)d_in[2];
    float* out = (float*)d_out;

    const size_t xt_bytes = (size_t)N_ * B_ * C_ * sizeof(float); // 204.8 MB

    if (ws_size >= xt_bytes) {
        float* xt = (float*)d_ws;
        transpose_kernel<<<N_, 256, 0, stream>>>(x, xt);
        gather_kernel<<<M_ / GPM, 256, 0, stream>>>(xt, cols, vals, out);
    } else {
        const int total = B_ * M_ * (C_ / 4);
        mesh_gather_direct<<<(total + 255) / 256, 256, 0, stream>>>(x, cols, vals, out);
    }
}

// Round 4
// 303.672 us; speedup vs baseline: 1.2403x; 1.2403x over previous
//
#include <hip/hip_runtime.h>

// out[b,m,c] = sum_{k<3} vals[m,k] * x[b, cols[m,k], c]
// B=8, N=50000, C=128, M=25000, K=3, fp32.
//
// Single-pass direct gather, plus:
//  - 2 m's per thread (m, m+M/2): 6 independent gather loads in flight (MLP).
//  - non-temporal stores for out: keep the 102 MB write stream out of L2/L3
//    so x (204.8 MB, fits the 256 MB L3) keeps its ~1.5x reuse resident.
// Uses clang ext_vector float4 (v4f) because __builtin_nontemporal_store
// rejects HIP_vector_type.

#define B_ 8
#define N_ 50000
#define C_ 128
#define M_ 25000
#define MH 12500   // M/2

typedef float v4f __attribute__((ext_vector_type(4)));

__global__ __launch_bounds__(256) void mesh_gather_kernel(
    const float* __restrict__ x,      // [B, N, C]
    const int* __restrict__ cols,     // [M, 3]
    const float* __restrict__ vals,   // [M, 3]
    float* __restrict__ out)          // [B, M, C]
{
    int t = blockIdx.x * blockDim.x + threadIdx.x;   // < B*MH*32 = 3.2M
    const int total = B_ * MH * (C_ / 4);
    if (t >= total) return;

    int c4 = t & 31;                 // float4 index within row
    int mh = (t >> 5) % MH;
    int b  = t / (MH * 32);

    int m0 = mh;
    int m1 = mh + MH;

    // hoist all index/weight loads first
    int i00 = cols[m0 * 3 + 0];
    int i01 = cols[m0 * 3 + 1];
    int i02 = cols[m0 * 3 + 2];
    int i10 = cols[m1 * 3 + 0];
    int i11 = cols[m1 * 3 + 1];
    int i12 = cols[m1 * 3 + 2];
    float v00 = vals[m0 * 3 + 0];
    float v01 = vals[m0 * 3 + 1];
    float v02 = vals[m0 * 3 + 2];
    float v10 = vals[m1 * 3 + 0];
    float v11 = vals[m1 * 3 + 1];
    float v12 = vals[m1 * 3 + 2];

    const v4f* xb = (const v4f*)(x + (long long)b * N_ * C_);

    // 6 independent gather loads in flight
    v4f a0 = xb[(long long)i00 * 32 + c4];
    v4f a1 = xb[(long long)i01 * 32 + c4];
    v4f a2 = xb[(long long)i02 * 32 + c4];
    v4f b0 = xb[(long long)i10 * 32 + c4];
    v4f b1 = xb[(long long)i11 * 32 + c4];
    v4f b2 = xb[(long long)i12 * 32 + c4];

    v4f r0 = v00 * a0 + v01 * a1 + v02 * a2;
    v4f r1 = v10 * b0 + v11 * b1 + v12 * b2;

    v4f* out4 = (v4f*)out;
    long long o0 = ((long long)b * M_ + m0) * 32 + c4;
    long long o1 = ((long long)b * M_ + m1) * 32 + c4;
    __builtin_nontemporal_store(r0, &out4[o0]);
    __builtin_nontemporal_store(r1, &out4[o1]);
}

extern "C" void kernel_launch(void* const* d_in, const int* in_sizes, int n_in,
                              void* d_out, int out_size, void* d_ws, size_t ws_size,
                              hipStream_t stream) {
    const float* x    = (const float*)d_in[0];
    const int*   cols = (const int*)d_in[1];
    const float* vals = (const float*)d_in[2];
    float* out = (float*)d_out;

    const int total = B_ * MH * (C_ / 4);   // 3,200,000
    const int block = 256;
    const int grid = (total + block - 1) / block;  // 12500
    mesh_gather_kernel<<<grid, block, 0, stream>>>(x, cols, vals, out);
}